// Round 7
// baseline (340.131 us; speedup 1.0000x reference)
//
#include <hip/hip_runtime.h>
#include <math.h>

#define N_NODES 32768
#define N_EDGES 524288
#define IN_F    256
#define OUT_F   128
#define NB      4

#define NE_BLK   (N_EDGES / 256)          // 2048
#define CONV_BLK (N_NODES * IN_F / 1024)  // 8192
#define GX_BLK   (N_NODES / 4)            // 8192 gather blocks
#define GEMM_BLK (N_NODES / 128)          // 256 gemm blocks
#define M_BLK    (N_NODES / 256)          // 128 m-prop blocks

typedef __attribute__((ext_vector_type(8))) short bf16x8;
typedef __attribute__((ext_vector_type(4))) float f32x4;

__device__ __forceinline__ ushort f2b(float f) {  // f32 -> bf16 RNE
    uint u = __float_as_uint(f);
    return (ushort)((u + 0x7fffu + ((u >> 16) & 1u)) >> 16);
}
__device__ __forceinline__ float b2f_lo(uint v) { return __uint_as_float(v << 16); }
__device__ __forceinline__ float b2f_hi(uint v) { return __uint_as_float(v & 0xffff0000u); }

__device__ __forceinline__ float softmax_gate(const float* bg, const float* temp, int i) {
    float T = temp[0];
    float mx = fmaxf(fmaxf(bg[0], bg[1]), fmaxf(bg[2], bg[3]));
    float e0 = expf((bg[0] - mx) / T), e1 = expf((bg[1] - mx) / T);
    float e2 = expf((bg[2] - mx) / T), e3 = expf((bg[3] - mx) / T);
    float s = e0 + e1 + e2 + e3;
    float ei = (i == 0) ? e0 : (i == 1) ? e1 : (i == 2) ? e2 : e3;
    return ei / s;
}

// per-block edge-layout detection: 1 -> int32 layout, 0 -> int64.
// wave 0 samples the odd 32-bit words of the first 64 presumed-int64 values.
__device__ __forceinline__ int detect_i32(const int* __restrict__ ei, int* sflag) {
    if (threadIdx.x < 64) {
        unsigned long long b = __ballot(ei[2 * threadIdx.x + 1] != 0);
        if (threadIdx.x == 0) *sflag = (b != 0ull) ? 1 : 0;
    }
    __syncthreads();
    return *sflag;
}

// ---------------------------------------------------------------------------
// K1: blocks [0,2048) degree count; [2048,10240) x->bf16; [10240,10304) WcT;
//     [10304,10336) WzT; [10336,10344) u / cvec.
// ---------------------------------------------------------------------------
__global__ __launch_bounds__(256) void count_prep_kernel(
    const int* __restrict__ ei, int* __restrict__ deg,
    const float* __restrict__ x, ushort* __restrict__ xb,
    const float* __restrict__ Wb, const float* __restrict__ W1,
    const float* __restrict__ W2, const float* __restrict__ Wo,
    const float* __restrict__ bb, const float* __restrict__ b2,
    const float* __restrict__ bo, const float* __restrict__ bg,
    const float* __restrict__ temp,
    ushort* __restrict__ WcT, ushort* __restrict__ WzT,
    float* __restrict__ u, float* __restrict__ cvec) {
    __shared__ float smem[16 * 128];
    __shared__ int sflag;
    int b = blockIdx.x;
    int tid = threadIdx.x;
    if (b < NE_BLK) {  // ---- degree count
        int i32 = detect_i32(ei, &sflag);
        int e = b * 256 + tid;
        int c = (i32 == 0) ? ei[2 * (N_EDGES + e)] : ei[N_EDGES + e];
        atomicAdd(&deg[c], 1);
        return;
    }
    b -= NE_BLK;
    if (b < CONV_BLK) {  // ---- x f32 -> bf16
        int idx = b * 256 + tid;
        float4 v = ((const float4*)x)[idx];
        ushort4 o;
        o.x = f2b(v.x); o.y = f2b(v.y); o.z = f2b(v.z); o.w = f2b(v.w);
        ((ushort4*)xb)[idx] = o;
        return;
    }
    b -= CONV_BLK;
    int f = tid & 127, rh = tid >> 7;
    if (b < 64) {  // ---- WcT[i][f][k] = sum_j Wb[i][k][j]*W1[i][j][f]
        int i = b >> 4, k0 = (b & 15) * 16;
#pragma unroll
        for (int rr = 0; rr < 8; rr++)
            smem[(rh * 8 + rr) * 128 + f] = Wb[((size_t)i * IN_F + k0 + rh * 8 + rr) * OUT_F + f];
        __syncthreads();
        float acc[8] = {};
        const float* W1i = W1 + (size_t)i * OUT_F * OUT_F;
        for (int j = 0; j < OUT_F; j++) {
            float w1 = W1i[j * OUT_F + f];
#pragma unroll
            for (int rr = 0; rr < 8; rr++) acc[rr] += smem[(rh * 8 + rr) * 128 + j] * w1;
        }
        ushort tmp[8];
#pragma unroll
        for (int rr = 0; rr < 8; rr++) tmp[rr] = f2b(acc[rr]);
        *(uint4*)(WcT + ((size_t)i * OUT_F + f) * IN_F + k0 + rh * 8) = *(uint4*)tmp;
    } else if (b < 96) {  // ---- WzT[f][128i+j] = g_i*sum_l W2[i][j][l]*Wo[128i+l][f]
        int id = b - 64;
        int i = id >> 3, j0 = (id & 7) * 16;
#pragma unroll
        for (int rr = 0; rr < 8; rr++)
            smem[(rh * 8 + rr) * 128 + f] = W2[((size_t)i * OUT_F + j0 + rh * 8 + rr) * OUT_F + f];
        __syncthreads();
        float acc[8] = {};
        for (int l = 0; l < OUT_F; l++) {
            float wo = Wo[((size_t)i * OUT_F + l) * OUT_F + f];
#pragma unroll
            for (int rr = 0; rr < 8; rr++) acc[rr] += smem[(rh * 8 + rr) * 128 + l] * wo;
        }
        float g = softmax_gate(bg, temp, i);
        ushort tmp[8];
#pragma unroll
        for (int rr = 0; rr < 8; rr++) tmp[rr] = f2b(g * acc[rr]);
        *(uint4*)(WzT + (size_t)f * (NB * OUT_F) + i * OUT_F + j0 + rh * 8) = *(uint4*)tmp;
    } else {  // ---- u (blocks 0..3) / cvec (blocks 4..7, atomic into pre-zeroed)
        int id = b - 96;
        int jc = rh;
        if (id < NB) {
            int i = id;
            float partial = 0.f;
            for (int j = jc * 64; j < jc * 64 + 64; j++)
                partial += bb[i * OUT_F + j] * W1[((size_t)i * OUT_F + j) * OUT_F + f];
            smem[jc * 128 + f] = partial;
            __syncthreads();
            if (jc == 0) u[i * OUT_F + f] = smem[f] + smem[128 + f];
        } else {
            int i = id - NB;
            float partial = 0.f;
            for (int j = jc * 64; j < jc * 64 + 64; j++)
                partial += b2[i * OUT_F + j] * Wo[((size_t)i * OUT_F + j) * OUT_F + f];
            smem[jc * 128 + f] = partial;
            __syncthreads();
            if (jc == 0) {
                float tot = (smem[f] + smem[128 + f]) * softmax_gate(bg, temp, i);
                if (i == 0) tot += bo[f];
                atomicAdd(&cvec[f], tot);
            }
        }
    }
}

// ---------------------------------------------------------------------------
// 3-phase parallel exclusive scan of deg[32768]
// ---------------------------------------------------------------------------
__global__ __launch_bounds__(256) void scan1_kernel(const int* __restrict__ deg,
                                                    int* __restrict__ bsum) {
    int t = threadIdx.x;
    int v = deg[blockIdx.x * 256 + t];
    __shared__ int red[4];
    int lane = t & 63, wv = t >> 6;
#pragma unroll
    for (int off = 32; off > 0; off >>= 1) v += __shfl_down(v, off);
    if (lane == 0) red[wv] = v;
    __syncthreads();
    if (t == 0) bsum[blockIdx.x] = red[0] + red[1] + red[2] + red[3];
}

__global__ __launch_bounds__(128) void scan2_kernel(const int* __restrict__ bsum,
                                                    int* __restrict__ bbase,
                                                    int* __restrict__ offs) {
    __shared__ int s[128];
    int t = threadIdx.x;
    int v = bsum[t];
    s[t] = v;
    __syncthreads();
    for (int off = 1; off < 128; off <<= 1) {
        int add = (t >= off) ? s[t - off] : 0;
        __syncthreads();
        s[t] += add;
        __syncthreads();
    }
    bbase[t] = s[t] - v;
    if (t == 127) offs[N_NODES] = s[127];
}

__global__ __launch_bounds__(256) void scan3_kernel(
    const int* __restrict__ deg, const int* __restrict__ bbase,
    int* __restrict__ offs, int* __restrict__ cursor,
    float* __restrict__ invd, float* __restrict__ m1) {
    __shared__ int s[256];
    int t = threadIdx.x;
    int idx = blockIdx.x * 256 + t;
    int d = deg[idx];
    s[t] = d;
    __syncthreads();
    for (int off = 1; off < 256; off <<= 1) {
        int add = (t >= off) ? s[t - off] : 0;
        __syncthreads();
        s[t] += add;
        __syncthreads();
    }
    int excl = bbase[blockIdx.x] + s[t] - d;
    offs[idx] = excl;
    cursor[idx] = excl;
    invd[idx] = 1.0f / (float)((d > 1) ? d : 1);
    m1[idx] = (d > 0) ? 1.0f : 0.0f;  // A . ones
}

// K4: pure CSR fill (per-block layout detection)
__global__ __launch_bounds__(256) void fill_kernel(
    const int* __restrict__ ei, int* __restrict__ cursor, int* __restrict__ srcs) {
    __shared__ int sflag;
    int i32 = detect_i32(ei, &sflag);
    int e = blockIdx.x * 256 + threadIdx.x;
    int r, c;
    if (i32 == 0) { r = ei[2 * e]; c = ei[2 * (N_EDGES + e)]; }
    else          { r = ei[e];     c = ei[N_EDGES + e]; }
    int slot = atomicAdd(&cursor[c], 1);
    srcs[slot] = r;
}

// ---------------------------------------------------------------------------
// Gather macros
// ---------------------------------------------------------------------------
#define ACC8(A, V)                                                              \
    A[0] += b2f_lo(V.x); A[1] += b2f_hi(V.x);                                   \
    A[2] += b2f_lo(V.y); A[3] += b2f_hi(V.y);                                   \
    A[4] += b2f_lo(V.z); A[5] += b2f_hi(V.z);                                   \
    A[6] += b2f_lo(V.w); A[7] += b2f_hi(V.w)

#define GATHER_256(INBUF)                                                       \
    float a0[8] = {0.f,0.f,0.f,0.f,0.f,0.f,0.f,0.f};                            \
    float a1[8] = {0.f,0.f,0.f,0.f,0.f,0.f,0.f,0.f};                            \
    int p = s;                                                                  \
    for (; p + 8 <= e; p += 8) {                                                \
        int base = p + 4 * half;                                                \
        int2 s01 = *(const int2*)(srcs + base);                                 \
        int2 s23 = *(const int2*)(srcs + base + 2);                             \
        uint4 v0 = *(const uint4*)(INBUF + (size_t)s01.x * IN_F + fl * 8);      \
        uint4 v1 = *(const uint4*)(INBUF + (size_t)s01.y * IN_F + fl * 8);      \
        uint4 v2 = *(const uint4*)(INBUF + (size_t)s23.x * IN_F + fl * 8);      \
        uint4 v3 = *(const uint4*)(INBUF + (size_t)s23.y * IN_F + fl * 8);      \
        ACC8(a0, v0); ACC8(a1, v1); ACC8(a0, v2); ACC8(a1, v3);                 \
    }                                                                           \
    for (; p + 4 <= e; p += 4) {                                                \
        int2 ss = *(const int2*)(srcs + p + 2 * half);                          \
        uint4 v0 = *(const uint4*)(INBUF + (size_t)ss.x * IN_F + fl * 8);       \
        uint4 v1 = *(const uint4*)(INBUF + (size_t)ss.y * IN_F + fl * 8);       \
        ACC8(a0, v0); ACC8(a1, v1);                                             \
    }                                                                           \
    for (; p + half < e; p += 2) {                                              \
        int src = srcs[p + half];                                               \
        uint4 v0 = *(const uint4*)(INBUF + (size_t)src * IN_F + fl * 8);        \
        ACC8(a0, v0);                                                           \
    }                                                                           \
    _Pragma("unroll") for (int k = 0; k < 8; k++) a0[k] += a1[k];               \
    _Pragma("unroll") for (int k = 0; k < 8; k++) a0[k] += __shfl_down(a0[k], 32);

// 128x128 MFMA tile over K=256, with epilogue: relu(acc + mval*u + b1) -> R col
#define GEMM_TILE_BODY(APTR, WTPTR, UPTR, BPTR, MEXPR, RCOL)                    \
    int m0 = gblk * 128;                                                        \
    int wv = tid >> 6, lane = tid & 63, quad = lane >> 4, lm = lane & 15;       \
    f32x4 acc[2][8];                                                            \
    f32x4 zero = {0.f, 0.f, 0.f, 0.f};                                          \
    _Pragma("unroll") for (int i = 0; i < 2; i++)                               \
        _Pragma("unroll") for (int j = 0; j < 8; j++) acc[i][j] = zero;         \
    for (int k0 = 0; k0 < IN_F; k0 += 64) {                                     \
        __syncthreads();                                                        \
        _Pragma("unroll") for (int it = 0; it < 4; it++) {                      \
            int c = tid + 256 * it;                                             \
            int r = c >> 3, c8 = c & 7;                                         \
            *(uint4*)&As[r][c8 * 8] =                                           \
                *(const uint4*)(APTR + (size_t)(m0 + r) * IN_F + k0 + c8 * 8);  \
            *(uint4*)&Bs[r][c8 * 8] =                                           \
                *(const uint4*)(WTPTR + (size_t)r * IN_F + k0 + c8 * 8);        \
        }                                                                       \
        __syncthreads();                                                        \
        _Pragma("unroll") for (int ks = 0; ks < 2; ks++) {                      \
            bf16x8 af0 = *(const bf16x8*)&As[wv * 32 + lm][ks * 32 + quad * 8]; \
            bf16x8 af1 = *(const bf16x8*)&As[wv * 32 + 16 + lm][ks * 32 + quad * 8]; \
            _Pragma("unroll") for (int nt = 0; nt < 8; nt++) {                  \
                bf16x8 bf = *(const bf16x8*)&Bs[nt * 16 + lm][ks * 32 + quad * 8]; \
                acc[0][nt] = __builtin_amdgcn_mfma_f32_16x16x32_bf16(af0, bf, acc[0][nt], 0, 0, 0); \
                acc[1][nt] = __builtin_amdgcn_mfma_f32_16x16x32_bf16(af1, bf, acc[1][nt], 0, 0, 0); \
            }                                                                   \
        }                                                                       \
    }                                                                           \
    float uv[8], bv[8];                                                         \
    _Pragma("unroll") for (int nt = 0; nt < 8; nt++) {                          \
        int col = nt * 16 + lm;                                                 \
        uv[nt] = UPTR[col];                                                     \
        bv[nt] = BPTR[col];                                                     \
    }                                                                           \
    _Pragma("unroll") for (int mt = 0; mt < 2; mt++)                            \
        _Pragma("unroll") for (int r = 0; r < 4; r++) {                         \
            int row = m0 + wv * 32 + mt * 16 + quad * 4 + r;                    \
            float mval = (MEXPR);                                               \
            _Pragma("unroll") for (int nt = 0; nt < 8; nt++) {                  \
                int col = nt * 16 + lm;                                         \
                float h = acc[mt][nt][r] + mval * uv[nt] + bv[nt];              \
                R[(size_t)row * (NB * OUT_F) + (RCOL) + col] = f2b(fmaxf(h, 0.f)); \
            }                                                                   \
        }

// K5: blocks [0,256) gemmP y=0 (xb.Wc0 -> R col0); [256,8448) X1 = A.x gather;
//     [8448,8576) m2 = A.m1
__global__ __launch_bounds__(256) void prop_x_gemm0_kernel(
    const ushort* __restrict__ xb, ushort* __restrict__ X1b,
    const float* __restrict__ m1, float* __restrict__ m2,
    const ushort* __restrict__ WcT, const float* __restrict__ u,
    const float* __restrict__ b1, ushort* __restrict__ R,
    const int* __restrict__ offs, const int* __restrict__ srcs,
    const float* __restrict__ invd) {
    __shared__ ushort As[128][72];
    __shared__ ushort Bs[128][72];
    int blk = blockIdx.x;
    int tid = threadIdx.x;
    if (blk < GEMM_BLK) {  // gemmP y=0, m==1
        int gblk = blk;
        GEMM_TILE_BODY(xb, WcT, u, b1, 1.0f, 0)
        return;
    }
    blk -= GEMM_BLK;
    if (blk >= GX_BLK) {  // m2 = A.m1
        int n = (blk - GX_BLK) * 256 + tid;
        int s = offs[n], e = offs[n + 1];
        float sum = 0.f;
        for (int p = s; p < e; ++p) sum += m1[srcs[p]];
        m2[n] = sum * invd[n];
        return;
    }
    int node = blk * 4 + (tid >> 6);
    int lane = tid & 63;
    int half = lane >> 5, fl = lane & 31;
    int s = offs[node], e = offs[node + 1];
    GATHER_256(xb);
    if (half == 0) {
        float w = invd[node];
        uint4 o;
        o.x = (uint)f2b(a0[0] * w) | ((uint)f2b(a0[1] * w) << 16);
        o.y = (uint)f2b(a0[2] * w) | ((uint)f2b(a0[3] * w) << 16);
        o.z = (uint)f2b(a0[4] * w) | ((uint)f2b(a0[5] * w) << 16);
        o.w = (uint)f2b(a0[6] * w) | ((uint)f2b(a0[7] * w) << 16);
        *(uint4*)(X1b + (size_t)node * IN_F + fl * 8) = o;
    }
}

// K6: gemmP y=2,3: X1.Wc{2,3} raw -> PQ halves
__global__ __launch_bounds__(256) void gemmP23_kernel(
    const ushort* __restrict__ X1b, const ushort* __restrict__ WcT,
    ushort* __restrict__ PQ) {
    int y = blockIdx.y + 2;
    const ushort* WT = WcT + (size_t)y * OUT_F * IN_F;
    int m0 = blockIdx.x * 128;
    __shared__ ushort As[128][72];
    __shared__ ushort Bs[128][72];
    int tid = threadIdx.x;
    int wv = tid >> 6, lane = tid & 63, quad = lane >> 4, lm = lane & 15;
    f32x4 acc[2][8];
    f32x4 zero = {0.f, 0.f, 0.f, 0.f};
#pragma unroll
    for (int i = 0; i < 2; i++)
#pragma unroll
        for (int j = 0; j < 8; j++) acc[i][j] = zero;
    for (int k0 = 0; k0 < IN_F; k0 += 64) {
        __syncthreads();
#pragma unroll
        for (int it = 0; it < 4; it++) {
            int c = tid + 256 * it;
            int r = c >> 3, c8 = c & 7;
            *(uint4*)&As[r][c8 * 8] = *(const uint4*)(X1b + (size_t)(m0 + r) * IN_F + k0 + c8 * 8);
            *(uint4*)&Bs[r][c8 * 8] = *(const uint4*)(WT + (size_t)r * IN_F + k0 + c8 * 8);
        }
        __syncthreads();
#pragma unroll
        for (int ks = 0; ks < 2; ks++) {
            bf16x8 af0 = *(const bf16x8*)&As[wv * 32 + lm][ks * 32 + quad * 8];
            bf16x8 af1 = *(const bf16x8*)&As[wv * 32 + 16 + lm][ks * 32 + quad * 8];
#pragma unroll
            for (int nt = 0; nt < 8; nt++) {
                bf16x8 bf = *(const bf16x8*)&Bs[nt * 16 + lm][ks * 32 + quad * 8];
                acc[0][nt] = __builtin_amdgcn_mfma_f32_16x16x32_bf16(af0, bf, acc[0][nt], 0, 0, 0);
                acc[1][nt] = __builtin_amdgcn_mfma_f32_16x16x32_bf16(af1, bf, acc[1][nt], 0, 0, 0);
            }
        }
    }
    int pqoff = (y - 2) * OUT_F;
#pragma unroll
    for (int mt = 0; mt < 2; mt++)
#pragma unroll
        for (int r = 0; r < 4; r++) {
            int row = m0 + wv * 32 + mt * 16 + quad * 4 + r;
#pragma unroll
            for (int nt = 0; nt < 8; nt++) {
                int col = nt * 16 + lm;
                PQ[(size_t)row * IN_F + pqoff + col] = f2b(acc[mt][nt][r]);
            }
        }
}

// K7: blocks [0,256) gemmP y=1 (X1.Wc1 + m1*u1 -> R col1);
//     [256,8448) A.[P2|Q3] gather (branch-2 epilogue -> R col2, Q' -> Qp);
//     [8448,8576) m3 = A.m2
__global__ __launch_bounds__(256) void prop_pq_gemm1_kernel(
    const ushort* __restrict__ PQ, const ushort* __restrict__ X1b,
    ushort* __restrict__ R, ushort* __restrict__ Qp,
    const float* __restrict__ m1, const float* __restrict__ m2,
    float* __restrict__ m3,
    const ushort* __restrict__ WcT, const float* __restrict__ u,
    const float* __restrict__ b1,
    const int* __restrict__ offs, const int* __restrict__ srcs,
    const float* __restrict__ invd) {
    __shared__ ushort As[128][72];
    __shared__ ushort Bs[128][72];
    int blk = blockIdx.x;
    int tid = threadIdx.x;
    if (blk < GEMM_BLK) {  // gemmP y=1
        int gblk = blk;
        const ushort* WT1 = WcT + (size_t)1 * OUT_F * IN_F;
        const float* u1 = u + OUT_F;
        const float* b11 = b1 + OUT_F;
        GEMM_TILE_BODY(X1b, WT1, u1, b11, m1[row], OUT_F)
        return;
    }
    blk -= GEMM_BLK;
    if (blk >= GX_BLK) {  // m3 = A.m2
        int n = (blk - GX_BLK) * 256 + tid;
        int s = offs[n], e = offs[n + 1];
        float sum = 0.f;
        for (int p = s; p < e; ++p) sum += m2[srcs[p]];
        m3[n] = sum * invd[n];
        return;
    }
    int node = blk * 4 + (tid >> 6);
    int lane = tid & 63;
    int half = lane >> 5, fl = lane & 31;
    int s = offs[node], e = offs[node + 1];
    GATHER_256(PQ);
    if (half == 0) {
        float w = invd[node];
        if (fl < 16) {  // branch 2: relu(A.P2 + m2*u2 + b1_2) -> R col 256+
            int col = fl * 8;
            float mv = m2[node];
            const float* u2 = u + 2 * OUT_F;
            const float* b12 = b1 + 2 * OUT_F;
            float4 ua = *(const float4*)(u2 + col);
            float4 ub = *(const float4*)(u2 + col + 4);
            float4 ba = *(const float4*)(b12 + col);
            float4 bb_ = *(const float4*)(b12 + col + 4);
            float o_[8];
            o_[0] = fmaxf(a0[0] * w + mv * ua.x + ba.x, 0.f);
            o_[1] = fmaxf(a0[1] * w + mv * ua.y + ba.y, 0.f);
            o_[2] = fmaxf(a0[2] * w + mv * ua.z + ba.z, 0.f);
            o_[3] = fmaxf(a0[3] * w + mv * ua.w + ba.w, 0.f);
            o_[4] = fmaxf(a0[4] * w + mv * ub.x + bb_.x, 0.f);
            o_[5] = fmaxf(a0[5] * w + mv * ub.y + bb_.y, 0.f);
            o_[6] = fmaxf(a0[6] * w + mv * ub.z + bb_.z, 0.f);
            o_[7] = fmaxf(a0[7] * w + mv * ub.w + bb_.w, 0.f);
            uint4 o;
            o.x = (uint)f2b(o_[0]) | ((uint)f2b(o_[1]) << 16);
            o.y = (uint)f2b(o_[2]) | ((uint)f2b(o_[3]) << 16);
            o.z = (uint)f2b(o_[4]) | ((uint)f2b(o_[5]) << 16);
            o.w = (uint)f2b(o_[6]) | ((uint)f2b(o_[7]) << 16);
            *(uint4*)(R + (size_t)node * (NB * OUT_F) + 2 * OUT_F + col) = o;
        } else {  // branch 3 intermediate: Q' = A.Q3 raw
            int col = (fl - 16) * 8;
            uint4 o;
            o.x = (uint)f2b(a0[0] * w) | ((uint)f2b(a0[1] * w) << 16);
            o.y = (uint)f2b(a0[2] * w) | ((uint)f2b(a0[3] * w) << 16);
            o.z = (uint)f2b(a0[4] * w) | ((uint)f2b(a0[5] * w) << 16);
            o.w = (uint)f2b(a0[6] * w) | ((uint)f2b(a0[7] * w) << 16);
            *(uint4*)(Qp + (size_t)node * OUT_F + col) = o;
        }
    }
}

// K8: prop3 on Qp (128-dim rows): quarter-wave per edge, branch-3 epilogue
__global__ __launch_bounds__(256) void prop_q_kernel(
    const ushort* __restrict__ Qp, ushort* __restrict__ R,
    const float* __restrict__ m3, const float* __restrict__ u3,
    const float* __restrict__ b13,
    const int* __restrict__ offs, const int* __restrict__ srcs,
    const float* __restrict__ invd) {
    int node = blockIdx.x * 4 + (threadIdx.x >> 6);
    int lane = threadIdx.x & 63;
    int q = lane >> 4, fl = lane & 15;
    int s = offs[node], e = offs[node + 1];
    float a[8] = {0.f,0.f,0.f,0.f,0.f,0.f,0.f,0.f};
    float b[8] = {0.f,0.f,0.f,0.f,0.f,0.f,0.f,0.f};
    int p = s;
    for (; p + 8 <= e; p += 8) {
        int2 ss = *(const int2*)(srcs + p + 2 * q);
        uint4 v0 = *(const uint4*)(Qp + (size_t)ss.x * OUT_F + fl * 8);
        uint4 v1 = *(const uint4*)(Qp + (size_t)ss.y * OUT_F + fl * 8);
        ACC8(a, v0); ACC8(b, v1);
    }
    for (; p + 4 <= e; p += 4) {
        int src = srcs[p + q];
        uint4 v0 = *(const uint4*)(Qp + (size_t)src * OUT_F + fl * 8);
        ACC8(a, v0);
    }
    if (p + q < e) {
        int src = srcs[p + q];
        uint4 v0 = *(const uint4*)(Qp + (size_t)src * OUT_F + fl * 8);
        ACC8(a, v0);
    }
#pragma unroll
    for (int k = 0; k < 8; k++) a[k] += b[k];
#pragma unroll
    for (int k = 0; k < 8; k++) a[k] += __shfl_down(a[k], 32);
#pragma unroll
    for (int k = 0; k < 8; k++) a[k] += __shfl_down(a[k], 16);
    if (lane < 16) {
        float w = invd[node];
        float mv = m3[node];
        int col = fl * 8;
        float4 ua = *(const float4*)(u3 + col);
        float4 ub = *(const float4*)(u3 + col + 4);
        float4 ba = *(const float4*)(b13 + col);
        float4 bb_ = *(const float4*)(b13 + col + 4);
        float o_[8];
        o_[0] = fmaxf(a[0] * w + mv * ua.x + ba.x, 0.f);
        o_[1] = fmaxf(a[1] * w + mv * ua.y + ba.y, 0.f);
        o_[2] = fmaxf(a[2] * w + mv * ua.z + ba.z, 0.f);
        o_[3] = fmaxf(a[3] * w + mv * ua.w + ba.w, 0.f);
        o_[4] = fmaxf(a[4] * w + mv * ub.x + bb_.x, 0.f);
        o_[5] = fmaxf(a[5] * w + mv * ub.y + bb_.y, 0.f);
        o_[6] = fmaxf(a[6] * w + mv * ub.z + bb_.z, 0.f);
        o_[7] = fmaxf(a[7] * w + mv * ub.w + bb_.w, 0.f);
        uint4 o;
        o.x = (uint)f2b(o_[0]) | ((uint)f2b(o_[1]) << 16);
        o.y = (uint)f2b(o_[2]) | ((uint)f2b(o_[3]) << 16);
        o.z = (uint)f2b(o_[4]) | ((uint)f2b(o_[5]) << 16);
        o.w = (uint)f2b(o_[6]) | ((uint)f2b(o_[7]) << 16);
        *(uint4*)(R + (size_t)node * (NB * OUT_F) + 3 * OUT_F + col) = o;
    }
}

// K9: out = R[32768,512](bf16) @ Wz(bf16) + c -> f32
__global__ __launch_bounds__(256) void gemm2_mfma_kernel(
    const ushort* __restrict__ R, const ushort* __restrict__ WzT,
    const float* __restrict__ cvec, float* __restrict__ out) {
    int m0 = blockIdx.x * 128;
    const int K = NB * OUT_F;  // 512
    __shared__ ushort As[128][72];
    __shared__ ushort Bs[128][72];
    int tid = threadIdx.x;
    int wv = tid >> 6, lane = tid & 63, quad = lane >> 4, lm = lane & 15;
    f32x4 acc[2][8];
    f32x4 zero = {0.f, 0.f, 0.f, 0.f};
#pragma unroll
    for (int i = 0; i < 2; i++)
#pragma unroll
        for (int j = 0; j < 8; j++) acc[i][j] = zero;
    for (int k0 = 0; k0 < K; k0 += 64) {
        __syncthreads();
#pragma unroll
        for (int it = 0; it < 4; it++) {
            int c = tid + 256 * it;
            int r = c >> 3, c8 = c & 7;
            *(uint4*)&As[r][c8 * 8] = *(const uint4*)(R + (size_t)(m0 + r) * K + k0 + c8 * 8);
            *(uint4*)&Bs[r][c8 * 8] = *(const uint4*)(WzT + (size_t)r * K + k0 + c8 * 8);
        }
        __syncthreads();
#pragma unroll
        for (int ks = 0; ks < 2; ks++) {
            bf16x8 af0 = *(const bf16x8*)&As[wv * 32 + lm][ks * 32 + quad * 8];
            bf16x8 af1 = *(const bf16x8*)&As[wv * 32 + 16 + lm][ks * 32 + quad * 8];
#pragma unroll
            for (int nt = 0; nt < 8; nt++) {
                bf16x8 bf = *(const bf16x8*)&Bs[nt * 16 + lm][ks * 32 + quad * 8];
                acc[0][nt] = __builtin_amdgcn_mfma_f32_16x16x32_bf16(af0, bf, acc[0][nt], 0, 0, 0);
                acc[1][nt] = __builtin_amdgcn_mfma_f32_16x16x32_bf16(af1, bf, acc[1][nt], 0, 0, 0);
            }
        }
    }
    float cb[8];
#pragma unroll
    for (int nt = 0; nt < 8; nt++) cb[nt] = cvec[nt * 16 + lm];
#pragma unroll
    for (int mt = 0; mt < 2; mt++)
#pragma unroll
        for (int r = 0; r < 4; r++) {
            int row = m0 + wv * 32 + mt * 16 + quad * 4 + r;
#pragma unroll
            for (int nt = 0; nt < 8; nt++) {
                int col = nt * 16 + lm;
                out[(size_t)row * OUT_F + col] = acc[mt][nt][r] + cb[nt];
            }
        }
}

// ---------------------------------------------------------------------------
extern "C" void kernel_launch(void* const* d_in, const int* in_sizes, int n_in,
                              void* d_out, int out_size, void* d_ws, size_t ws_size,
                              hipStream_t stream) {
    const float* x    = (const float*)d_in[0];
    const int*   ei   = (const int*)d_in[1];
    const float* Wb   = (const float*)d_in[2];
    const float* bb   = (const float*)d_in[3];
    const float* W1   = (const float*)d_in[4];
    const float* b1   = (const float*)d_in[5];
    const float* W2   = (const float*)d_in[6];
    const float* b2   = (const float*)d_in[7];
    const float* bg   = (const float*)d_in[8];
    const float* temp = (const float*)d_in[9];
    const float* Wo   = (const float*)d_in[10];
    const float* bo   = (const float*)d_in[11];
    float* out = (float*)d_out;

    char* w = (char*)d_ws;
    size_t used = 0;
    auto alloc = [&](size_t bytes) {
        char* p = w + used;
        used += (bytes + 255) & ~(size_t)255;
        return p;
    };
    // deg + cvec contiguous -> single memset zeroes both
    int*    deg    = (int*)alloc(N_NODES * 4);
    float*  cvec   = (float*)alloc(OUT_F * 4);
    int*    offs   = (int*)alloc((N_NODES + 2) * 4);
    int*    cursor = (int*)alloc(N_NODES * 4);
    int*    srcs   = (int*)alloc(N_EDGES * 4);
    int*    bsum   = (int*)alloc(128 * 4);
    int*    bbase  = (int*)alloc(128 * 4);
    float*  invd   = (float*)alloc(N_NODES * 4);
    float*  mbuf   = (float*)alloc((size_t)3 * N_NODES * 4);
    float*  u      = (float*)alloc(NB * OUT_F * 4);
    ushort* WcT    = (ushort*)alloc((size_t)NB * IN_F * OUT_F * 2);
    ushort* WzT    = (ushort*)alloc((size_t)NB * OUT_F * OUT_F * 2);
    ushort* xb     = (ushort*)alloc((size_t)N_NODES * IN_F * 2);
    ushort* X1b    = (ushort*)alloc((size_t)N_NODES * IN_F * 2);
    ushort* PQ     = (ushort*)alloc((size_t)N_NODES * IN_F * 2);
    ushort* Qp     = (ushort*)alloc((size_t)N_NODES * OUT_F * 2);
    ushort* R      = (ushort*)alloc((size_t)N_NODES * NB * OUT_F * 2);
    if (used > ws_size) return;

    float* m1v = mbuf;
    float* m2v = mbuf + N_NODES;
    float* m3v = mbuf + 2 * N_NODES;

    hipMemsetAsync(deg, 0, N_NODES * 4 + 512, stream);  // deg + cvec

    count_prep_kernel<<<NE_BLK + CONV_BLK + 104, 256, 0, stream>>>(
        ei, deg, x, xb, Wb, W1, W2, Wo, bb, b2, bo, bg, temp, WcT, WzT, u, cvec);
    scan1_kernel<<<N_NODES / 256, 256, 0, stream>>>(deg, bsum);
    scan2_kernel<<<1, 128, 0, stream>>>(bsum, bbase, offs);
    scan3_kernel<<<N_NODES / 256, 256, 0, stream>>>(deg, bbase, offs, cursor, invd, m1v);
    fill_kernel<<<NE_BLK, 256, 0, stream>>>(ei, cursor, srcs);

    // X1 = A.x + m2 = A.m1, co-scheduled with gemmP y=0
    prop_x_gemm0_kernel<<<GEMM_BLK + GX_BLK + M_BLK, 256, 0, stream>>>(
        xb, X1b, m1v, m2v, WcT, u, b1, R, offs, srcs, invd);
    // P2/Q3 staging
    {
        dim3 grid(GEMM_BLK, 2);
        gemmP23_kernel<<<grid, 256, 0, stream>>>(X1b, WcT, PQ);
    }
    // A.[P2|Q3] + m3 = A.m2, co-scheduled with gemmP y=1
    prop_pq_gemm1_kernel<<<GEMM_BLK + GX_BLK + M_BLK, 256, 0, stream>>>(
        PQ, X1b, R, Qp, m1v, m2v, m3v, WcT, u, b1, offs, srcs, invd);
    // A.Q' with branch-3 epilogue (128-dim gather)
    prop_q_kernel<<<N_NODES / 4, 256, 0, stream>>>(
        Qp, R, m3v, u + 3 * OUT_F, b1 + 3 * OUT_F, offs, srcs, invd);

    gemm2_mfma_kernel<<<N_NODES / 128, 256, 0, stream>>>(R, WzT, cvec, out);
}

// Round 8
// 282.805 us; speedup vs baseline: 1.2027x; 1.2027x over previous
//
#include <hip/hip_runtime.h>
#include <math.h>

#define N_NODES 32768
#define N_EDGES 524288
#define IN_F    256
#define OUT_F   128
#define NB      4
#define STRIDE  96                        // bucket stride; P(deg>96) ~ 0

#define NE_BLK   (N_EDGES / 256)          // 2048
#define CONV_BLK (N_NODES * IN_F / 1024)  // 8192
#define GX_BLK   (N_NODES / 4)            // 8192 gather blocks
#define GEMM_BLK (N_NODES / 128)          // 256 gemm blocks
#define M_BLK    (N_NODES / 256)          // 128 m-prop blocks

typedef __attribute__((ext_vector_type(8))) short bf16x8;
typedef __attribute__((ext_vector_type(4))) float f32x4;

__device__ __forceinline__ ushort f2b(float f) {  // f32 -> bf16 RNE
    uint u = __float_as_uint(f);
    return (ushort)((u + 0x7fffu + ((u >> 16) & 1u)) >> 16);
}
__device__ __forceinline__ float b2f_lo(uint v) { return __uint_as_float(v << 16); }
__device__ __forceinline__ float b2f_hi(uint v) { return __uint_as_float(v & 0xffff0000u); }

__device__ __forceinline__ float softmax_gate(const float* bg, const float* temp, int i) {
    float T = temp[0];
    float mx = fmaxf(fmaxf(bg[0], bg[1]), fmaxf(bg[2], bg[3]));
    float e0 = expf((bg[0] - mx) / T), e1 = expf((bg[1] - mx) / T);
    float e2 = expf((bg[2] - mx) / T), e3 = expf((bg[3] - mx) / T);
    float s = e0 + e1 + e2 + e3;
    float ei = (i == 0) ? e0 : (i == 1) ? e1 : (i == 2) ? e2 : e3;
    return ei / s;
}

// per-block edge-layout detection: 1 -> int32 layout, 0 -> int64.
__device__ __forceinline__ int detect_i32(const int* __restrict__ ei, int* sflag) {
    if (threadIdx.x < 64) {
        unsigned long long b = __ballot(ei[2 * threadIdx.x + 1] != 0);
        if (threadIdx.x == 0) *sflag = (b != 0ull) ? 1 : 0;
    }
    __syncthreads();
    return *sflag;
}

// ---------------------------------------------------------------------------
// K2 (after memset): blocks [0,2048) bucket-fill edges (deg = final cursor);
// [2048,10240) x->bf16; [10240,10304) WcT; [10304,10336) WzT; [10336,10344) u/cvec
// ---------------------------------------------------------------------------
__global__ __launch_bounds__(256) void fill_all_kernel(
    const int* __restrict__ ei, int* __restrict__ cursor, int* __restrict__ srcs,
    const float* __restrict__ x, ushort* __restrict__ xb,
    const float* __restrict__ Wb, const float* __restrict__ W1,
    const float* __restrict__ W2, const float* __restrict__ Wo,
    const float* __restrict__ bb, const float* __restrict__ b2,
    const float* __restrict__ bo, const float* __restrict__ bg,
    const float* __restrict__ temp,
    ushort* __restrict__ WcT, ushort* __restrict__ WzT,
    float* __restrict__ u, float* __restrict__ cvec) {
    __shared__ float smem[16 * 128];
    __shared__ int sflag;
    int b = blockIdx.x;
    int tid = threadIdx.x;
    if (b < NE_BLK) {  // ---- fill buckets
        int i32 = detect_i32(ei, &sflag);
        int e = b * 256 + tid;
        int r, c;
        if (i32 == 0) { r = ei[2 * e]; c = ei[2 * (N_EDGES + e)]; }
        else          { r = ei[e];     c = ei[N_EDGES + e]; }
        int slot = atomicAdd(&cursor[c], 1);
        if (slot < STRIDE) srcs[(size_t)c * STRIDE + slot] = r;
        return;
    }
    b -= NE_BLK;
    if (b < CONV_BLK) {  // ---- x f32 -> bf16
        int idx = b * 256 + tid;
        float4 v = ((const float4*)x)[idx];
        ushort4 o;
        o.x = f2b(v.x); o.y = f2b(v.y); o.z = f2b(v.z); o.w = f2b(v.w);
        ((ushort4*)xb)[idx] = o;
        return;
    }
    b -= CONV_BLK;
    int f = tid & 127, rh = tid >> 7;
    if (b < 64) {  // ---- WcT[i][f][k] = sum_j Wb[i][k][j]*W1[i][j][f]
        int i = b >> 4, k0 = (b & 15) * 16;
#pragma unroll
        for (int rr = 0; rr < 8; rr++)
            smem[(rh * 8 + rr) * 128 + f] = Wb[((size_t)i * IN_F + k0 + rh * 8 + rr) * OUT_F + f];
        __syncthreads();
        float acc[8] = {};
        const float* W1i = W1 + (size_t)i * OUT_F * OUT_F;
        for (int j = 0; j < OUT_F; j++) {
            float w1 = W1i[j * OUT_F + f];
#pragma unroll
            for (int rr = 0; rr < 8; rr++) acc[rr] += smem[(rh * 8 + rr) * 128 + j] * w1;
        }
        ushort tmp[8];
#pragma unroll
        for (int rr = 0; rr < 8; rr++) tmp[rr] = f2b(acc[rr]);
        *(uint4*)(WcT + ((size_t)i * OUT_F + f) * IN_F + k0 + rh * 8) = *(uint4*)tmp;
    } else if (b < 96) {  // ---- WzT[f][128i+j] = g_i*sum_l W2[i][j][l]*Wo[128i+l][f]
        int id = b - 64;
        int i = id >> 3, j0 = (id & 7) * 16;
#pragma unroll
        for (int rr = 0; rr < 8; rr++)
            smem[(rh * 8 + rr) * 128 + f] = W2[((size_t)i * OUT_F + j0 + rh * 8 + rr) * OUT_F + f];
        __syncthreads();
        float acc[8] = {};
        for (int l = 0; l < OUT_F; l++) {
            float wo = Wo[((size_t)i * OUT_F + l) * OUT_F + f];
#pragma unroll
            for (int rr = 0; rr < 8; rr++) acc[rr] += smem[(rh * 8 + rr) * 128 + l] * wo;
        }
        float g = softmax_gate(bg, temp, i);
        ushort tmp[8];
#pragma unroll
        for (int rr = 0; rr < 8; rr++) tmp[rr] = f2b(g * acc[rr]);
        *(uint4*)(WzT + (size_t)f * (NB * OUT_F) + i * OUT_F + j0 + rh * 8) = *(uint4*)tmp;
    } else {  // ---- u (blocks 0..3) / cvec (blocks 4..7, atomic into pre-zeroed)
        int id = b - 96;
        int jc = rh;
        if (id < NB) {
            int i = id;
            float partial = 0.f;
            for (int j = jc * 64; j < jc * 64 + 64; j++)
                partial += bb[i * OUT_F + j] * W1[((size_t)i * OUT_F + j) * OUT_F + f];
            smem[jc * 128 + f] = partial;
            __syncthreads();
            if (jc == 0) u[i * OUT_F + f] = smem[f] + smem[128 + f];
        } else {
            int i = id - NB;
            float partial = 0.f;
            for (int j = jc * 64; j < jc * 64 + 64; j++)
                partial += b2[i * OUT_F + j] * Wo[((size_t)i * OUT_F + j) * OUT_F + f];
            smem[jc * 128 + f] = partial;
            __syncthreads();
            if (jc == 0) {
                float tot = (smem[f] + smem[128 + f]) * softmax_gate(bg, temp, i);
                if (i == 0) tot += bo[f];
                atomicAdd(&cvec[f], tot);
            }
        }
    }
}

// ---------------------------------------------------------------------------
// Gather macros (bucketed CSR: s = node*STRIDE, e = s + min(deg,STRIDE))
// ---------------------------------------------------------------------------
#define ACC8(A, V)                                                              \
    A[0] += b2f_lo(V.x); A[1] += b2f_hi(V.x);                                   \
    A[2] += b2f_lo(V.y); A[3] += b2f_hi(V.y);                                   \
    A[4] += b2f_lo(V.z); A[5] += b2f_hi(V.z);                                   \
    A[6] += b2f_lo(V.w); A[7] += b2f_hi(V.w)

#define GATHER_256(INBUF)                                                       \
    float a0[8] = {0.f,0.f,0.f,0.f,0.f,0.f,0.f,0.f};                            \
    float a1[8] = {0.f,0.f,0.f,0.f,0.f,0.f,0.f,0.f};                            \
    int p = s;                                                                  \
    for (; p + 8 <= e; p += 8) {                                                \
        int base = p + 4 * half;                                                \
        int2 s01 = *(const int2*)(srcs + base);                                 \
        int2 s23 = *(const int2*)(srcs + base + 2);                             \
        uint4 v0 = *(const uint4*)(INBUF + (size_t)s01.x * IN_F + fl * 8);      \
        uint4 v1 = *(const uint4*)(INBUF + (size_t)s01.y * IN_F + fl * 8);      \
        uint4 v2 = *(const uint4*)(INBUF + (size_t)s23.x * IN_F + fl * 8);      \
        uint4 v3 = *(const uint4*)(INBUF + (size_t)s23.y * IN_F + fl * 8);      \
        ACC8(a0, v0); ACC8(a1, v1); ACC8(a0, v2); ACC8(a1, v3);                 \
    }                                                                           \
    for (; p + 4 <= e; p += 4) {                                                \
        int2 ss = *(const int2*)(srcs + p + 2 * half);                          \
        uint4 v0 = *(const uint4*)(INBUF + (size_t)ss.x * IN_F + fl * 8);       \
        uint4 v1 = *(const uint4*)(INBUF + (size_t)ss.y * IN_F + fl * 8);       \
        ACC8(a0, v0); ACC8(a1, v1);                                             \
    }                                                                           \
    for (; p + half < e; p += 2) {                                              \
        int src = srcs[p + half];                                               \
        uint4 v0 = *(const uint4*)(INBUF + (size_t)src * IN_F + fl * 8);        \
        ACC8(a0, v0);                                                           \
    }                                                                           \
    _Pragma("unroll") for (int k = 0; k < 8; k++) a0[k] += a1[k];               \
    _Pragma("unroll") for (int k = 0; k < 8; k++) a0[k] += __shfl_down(a0[k], 32);

// K3: blocks [0,8192) X1 = A.x; [8192,8320) m2 = A.m1 (m1 = deg>0, inline)
__global__ __launch_bounds__(256) void prop_x_kernel(
    const ushort* __restrict__ xb, ushort* __restrict__ X1b,
    const int* __restrict__ deg, float* __restrict__ m2,
    const int* __restrict__ srcs) {
    int blk = blockIdx.x;
    int tid = threadIdx.x;
    if (blk >= GX_BLK) {  // m2 = A.(deg>0)
        int n = (blk - GX_BLK) * 256 + tid;
        int d = deg[n];
        int s = n * STRIDE, e = s + ((d < STRIDE) ? d : STRIDE);
        float sum = 0.f;
        for (int p = s; p < e; ++p) sum += (deg[srcs[p]] > 0) ? 1.0f : 0.0f;
        m2[n] = sum / (float)((d > 1) ? d : 1);
        return;
    }
    int node = blk * 4 + (tid >> 6);
    int lane = tid & 63;
    int half = lane >> 5, fl = lane & 31;
    int d = deg[node];
    int s = node * STRIDE, e = s + ((d < STRIDE) ? d : STRIDE);
    GATHER_256(xb);
    if (half == 0) {
        float w = 1.0f / (float)((d > 1) ? d : 1);
        uint4 o;
        o.x = (uint)f2b(a0[0] * w) | ((uint)f2b(a0[1] * w) << 16);
        o.y = (uint)f2b(a0[2] * w) | ((uint)f2b(a0[3] * w) << 16);
        o.z = (uint)f2b(a0[4] * w) | ((uint)f2b(a0[5] * w) << 16);
        o.w = (uint)f2b(a0[6] * w) | ((uint)f2b(a0[7] * w) << 16);
        *(uint4*)(X1b + (size_t)node * IN_F + fl * 8) = o;
    }
}

// K4: gemmP grid(256,4): y=0: relu(xb.Wc0 + u0 + b1_0) -> R col0
//     y=1: relu(X1.Wc1 + (deg>0)*u1 + b1_1) -> R col1;  y=2,3: X1.Wc{2,3} -> PQ
__global__ __launch_bounds__(256) void gemmP_kernel(
    const ushort* __restrict__ xb, const ushort* __restrict__ X1b,
    const ushort* __restrict__ WcT, const float* __restrict__ u,
    const float* __restrict__ b1, const int* __restrict__ deg,
    ushort* __restrict__ R, ushort* __restrict__ PQ) {
    int y = blockIdx.y;
    const ushort* A = (y == 0) ? xb : X1b;
    const ushort* WT = WcT + (size_t)y * OUT_F * IN_F;
    int m0 = blockIdx.x * 128;
    __shared__ ushort As[128][72];
    __shared__ ushort Bs[128][72];
    int tid = threadIdx.x;
    int wv = tid >> 6, lane = tid & 63, quad = lane >> 4, lm = lane & 15;
    f32x4 acc[2][8];
    f32x4 zero = {0.f, 0.f, 0.f, 0.f};
#pragma unroll
    for (int i = 0; i < 2; i++)
#pragma unroll
        for (int j = 0; j < 8; j++) acc[i][j] = zero;
    for (int k0 = 0; k0 < IN_F; k0 += 64) {
        __syncthreads();
#pragma unroll
        for (int it = 0; it < 4; it++) {
            int c = tid + 256 * it;
            int r = c >> 3, c8 = c & 7;
            *(uint4*)&As[r][c8 * 8] = *(const uint4*)(A + (size_t)(m0 + r) * IN_F + k0 + c8 * 8);
            *(uint4*)&Bs[r][c8 * 8] = *(const uint4*)(WT + (size_t)r * IN_F + k0 + c8 * 8);
        }
        __syncthreads();
#pragma unroll
        for (int ks = 0; ks < 2; ks++) {
            bf16x8 af0 = *(const bf16x8*)&As[wv * 32 + lm][ks * 32 + quad * 8];
            bf16x8 af1 = *(const bf16x8*)&As[wv * 32 + 16 + lm][ks * 32 + quad * 8];
#pragma unroll
            for (int nt = 0; nt < 8; nt++) {
                bf16x8 bf = *(const bf16x8*)&Bs[nt * 16 + lm][ks * 32 + quad * 8];
                acc[0][nt] = __builtin_amdgcn_mfma_f32_16x16x32_bf16(af0, bf, acc[0][nt], 0, 0, 0);
                acc[1][nt] = __builtin_amdgcn_mfma_f32_16x16x32_bf16(af1, bf, acc[1][nt], 0, 0, 0);
            }
        }
    }
    if (y >= 2) {  // raw bf16 -> PQ halves
        int pqoff = (y - 2) * OUT_F;
#pragma unroll
        for (int mt = 0; mt < 2; mt++)
#pragma unroll
            for (int r = 0; r < 4; r++) {
                int row = m0 + wv * 32 + mt * 16 + quad * 4 + r;
#pragma unroll
                for (int nt = 0; nt < 8; nt++) {
                    int col = nt * 16 + lm;
                    PQ[(size_t)row * IN_F + pqoff + col] = f2b(acc[mt][nt][r]);
                }
            }
    } else {
        float uv[8], bv[8];
#pragma unroll
        for (int nt = 0; nt < 8; nt++) {
            int col = nt * 16 + lm;
            uv[nt] = u[y * OUT_F + col];
            bv[nt] = b1[y * OUT_F + col];
        }
#pragma unroll
        for (int mt = 0; mt < 2; mt++)
#pragma unroll
            for (int r = 0; r < 4; r++) {
                int row = m0 + wv * 32 + mt * 16 + quad * 4 + r;
                float mval = (y == 0) ? 1.0f : ((deg[row] > 0) ? 1.0f : 0.0f);
#pragma unroll
                for (int nt = 0; nt < 8; nt++) {
                    int col = nt * 16 + lm;
                    float h = acc[mt][nt][r] + mval * uv[nt] + bv[nt];
                    R[(size_t)row * (NB * OUT_F) + y * OUT_F + col] = f2b(fmaxf(h, 0.f));
                }
            }
    }
}

// K5: blocks [0,8192) A.[P2|Q3] (branch-2 epilogue -> R col2; Q' -> Qp);
//     [8192,8320) m3 = A.m2
__global__ __launch_bounds__(256) void prop_pq_kernel(
    const ushort* __restrict__ PQ, ushort* __restrict__ R, ushort* __restrict__ Qp,
    const int* __restrict__ deg, const float* __restrict__ m2, float* __restrict__ m3,
    const float* __restrict__ u2, const float* __restrict__ b12,
    const int* __restrict__ srcs) {
    int blk = blockIdx.x;
    int tid = threadIdx.x;
    if (blk >= GX_BLK) {  // m3 = A.m2
        int n = (blk - GX_BLK) * 256 + tid;
        int d = deg[n];
        int s = n * STRIDE, e = s + ((d < STRIDE) ? d : STRIDE);
        float sum = 0.f;
        for (int p = s; p < e; ++p) sum += m2[srcs[p]];
        m3[n] = sum / (float)((d > 1) ? d : 1);
        return;
    }
    int node = blk * 4 + (tid >> 6);
    int lane = tid & 63;
    int half = lane >> 5, fl = lane & 31;
    int d = deg[node];
    int s = node * STRIDE, e = s + ((d < STRIDE) ? d : STRIDE);
    GATHER_256(PQ);
    if (half == 0) {
        float w = 1.0f / (float)((d > 1) ? d : 1);
        if (fl < 16) {  // branch 2: relu(A.P2 + m2*u2 + b1_2) -> R col 256+
            int col = fl * 8;
            float mv = m2[node];
            float4 ua = *(const float4*)(u2 + col);
            float4 ub = *(const float4*)(u2 + col + 4);
            float4 ba = *(const float4*)(b12 + col);
            float4 bb_ = *(const float4*)(b12 + col + 4);
            float o_[8];
            o_[0] = fmaxf(a0[0] * w + mv * ua.x + ba.x, 0.f);
            o_[1] = fmaxf(a0[1] * w + mv * ua.y + ba.y, 0.f);
            o_[2] = fmaxf(a0[2] * w + mv * ua.z + ba.z, 0.f);
            o_[3] = fmaxf(a0[3] * w + mv * ua.w + ba.w, 0.f);
            o_[4] = fmaxf(a0[4] * w + mv * ub.x + bb_.x, 0.f);
            o_[5] = fmaxf(a0[5] * w + mv * ub.y + bb_.y, 0.f);
            o_[6] = fmaxf(a0[6] * w + mv * ub.z + bb_.z, 0.f);
            o_[7] = fmaxf(a0[7] * w + mv * ub.w + bb_.w, 0.f);
            uint4 o;
            o.x = (uint)f2b(o_[0]) | ((uint)f2b(o_[1]) << 16);
            o.y = (uint)f2b(o_[2]) | ((uint)f2b(o_[3]) << 16);
            o.z = (uint)f2b(o_[4]) | ((uint)f2b(o_[5]) << 16);
            o.w = (uint)f2b(o_[6]) | ((uint)f2b(o_[7]) << 16);
            *(uint4*)(R + (size_t)node * (NB * OUT_F) + 2 * OUT_F + col) = o;
        } else {  // branch 3 intermediate: Q' = A.Q3 raw
            int col = (fl - 16) * 8;
            uint4 o;
            o.x = (uint)f2b(a0[0] * w) | ((uint)f2b(a0[1] * w) << 16);
            o.y = (uint)f2b(a0[2] * w) | ((uint)f2b(a0[3] * w) << 16);
            o.z = (uint)f2b(a0[4] * w) | ((uint)f2b(a0[5] * w) << 16);
            o.w = (uint)f2b(a0[6] * w) | ((uint)f2b(a0[7] * w) << 16);
            *(uint4*)(Qp + (size_t)node * OUT_F + col) = o;
        }
    }
}

// K6: prop3 on Qp (128-dim rows): quarter-wave per edge, branch-3 epilogue
__global__ __launch_bounds__(256) void prop_q_kernel(
    const ushort* __restrict__ Qp, ushort* __restrict__ R,
    const int* __restrict__ deg, const float* __restrict__ m3,
    const float* __restrict__ u3, const float* __restrict__ b13,
    const int* __restrict__ srcs) {
    int node = blockIdx.x * 4 + (threadIdx.x >> 6);
    int lane = threadIdx.x & 63;
    int q = lane >> 4, fl = lane & 15;
    int d = deg[node];
    int s = node * STRIDE, e = s + ((d < STRIDE) ? d : STRIDE);
    float a[8] = {0.f,0.f,0.f,0.f,0.f,0.f,0.f,0.f};
    float b[8] = {0.f,0.f,0.f,0.f,0.f,0.f,0.f,0.f};
    int p = s;
    for (; p + 8 <= e; p += 8) {
        int2 ss = *(const int2*)(srcs + p + 2 * q);
        uint4 v0 = *(const uint4*)(Qp + (size_t)ss.x * OUT_F + fl * 8);
        uint4 v1 = *(const uint4*)(Qp + (size_t)ss.y * OUT_F + fl * 8);
        ACC8(a, v0); ACC8(b, v1);
    }
    for (; p + 4 <= e; p += 4) {
        int src = srcs[p + q];
        uint4 v0 = *(const uint4*)(Qp + (size_t)src * OUT_F + fl * 8);
        ACC8(a, v0);
    }
    if (p + q < e) {
        int src = srcs[p + q];
        uint4 v0 = *(const uint4*)(Qp + (size_t)src * OUT_F + fl * 8);
        ACC8(a, v0);
    }
#pragma unroll
    for (int k = 0; k < 8; k++) a[k] += b[k];
#pragma unroll
    for (int k = 0; k < 8; k++) a[k] += __shfl_down(a[k], 32);
#pragma unroll
    for (int k = 0; k < 8; k++) a[k] += __shfl_down(a[k], 16);
    if (lane < 16) {
        float w = 1.0f / (float)((d > 1) ? d : 1);
        float mv = m3[node];
        int col = fl * 8;
        float4 ua = *(const float4*)(u3 + col);
        float4 ub = *(const float4*)(u3 + col + 4);
        float4 ba = *(const float4*)(b13 + col);
        float4 bb_ = *(const float4*)(b13 + col + 4);
        float o_[8];
        o_[0] = fmaxf(a[0] * w + mv * ua.x + ba.x, 0.f);
        o_[1] = fmaxf(a[1] * w + mv * ua.y + ba.y, 0.f);
        o_[2] = fmaxf(a[2] * w + mv * ua.z + ba.z, 0.f);
        o_[3] = fmaxf(a[3] * w + mv * ua.w + ba.w, 0.f);
        o_[4] = fmaxf(a[4] * w + mv * ub.x + bb_.x, 0.f);
        o_[5] = fmaxf(a[5] * w + mv * ub.y + bb_.y, 0.f);
        o_[6] = fmaxf(a[6] * w + mv * ub.z + bb_.z, 0.f);
        o_[7] = fmaxf(a[7] * w + mv * ub.w + bb_.w, 0.f);
        uint4 o;
        o.x = (uint)f2b(o_[0]) | ((uint)f2b(o_[1]) << 16);
        o.y = (uint)f2b(o_[2]) | ((uint)f2b(o_[3]) << 16);
        o.z = (uint)f2b(o_[4]) | ((uint)f2b(o_[5]) << 16);
        o.w = (uint)f2b(o_[6]) | ((uint)f2b(o_[7]) << 16);
        *(uint4*)(R + (size_t)node * (NB * OUT_F) + 3 * OUT_F + col) = o;
    }
}

// K7: out = R[32768,512](bf16) @ Wz(bf16) + c -> f32
__global__ __launch_bounds__(256) void gemm2_mfma_kernel(
    const ushort* __restrict__ R, const ushort* __restrict__ WzT,
    const float* __restrict__ cvec, float* __restrict__ out) {
    int m0 = blockIdx.x * 128;
    const int K = NB * OUT_F;  // 512
    __shared__ ushort As[128][72];
    __shared__ ushort Bs[128][72];
    int tid = threadIdx.x;
    int wv = tid >> 6, lane = tid & 63, quad = lane >> 4, lm = lane & 15;
    f32x4 acc[2][8];
    f32x4 zero = {0.f, 0.f, 0.f, 0.f};
#pragma unroll
    for (int i = 0; i < 2; i++)
#pragma unroll
        for (int j = 0; j < 8; j++) acc[i][j] = zero;
    for (int k0 = 0; k0 < K; k0 += 64) {
        __syncthreads();
#pragma unroll
        for (int it = 0; it < 4; it++) {
            int c = tid + 256 * it;
            int r = c >> 3, c8 = c & 7;
            *(uint4*)&As[r][c8 * 8] = *(const uint4*)(R + (size_t)(m0 + r) * K + k0 + c8 * 8);
            *(uint4*)&Bs[r][c8 * 8] = *(const uint4*)(WzT + (size_t)r * K + k0 + c8 * 8);
        }
        __syncthreads();
#pragma unroll
        for (int ks = 0; ks < 2; ks++) {
            bf16x8 af0 = *(const bf16x8*)&As[wv * 32 + lm][ks * 32 + quad * 8];
            bf16x8 af1 = *(const bf16x8*)&As[wv * 32 + 16 + lm][ks * 32 + quad * 8];
#pragma unroll
            for (int nt = 0; nt < 8; nt++) {
                bf16x8 bf = *(const bf16x8*)&Bs[nt * 16 + lm][ks * 32 + quad * 8];
                acc[0][nt] = __builtin_amdgcn_mfma_f32_16x16x32_bf16(af0, bf, acc[0][nt], 0, 0, 0);
                acc[1][nt] = __builtin_amdgcn_mfma_f32_16x16x32_bf16(af1, bf, acc[1][nt], 0, 0, 0);
            }
        }
    }
    float cb[8];
#pragma unroll
    for (int nt = 0; nt < 8; nt++) cb[nt] = cvec[nt * 16 + lm];
#pragma unroll
    for (int mt = 0; mt < 2; mt++)
#pragma unroll
        for (int r = 0; r < 4; r++) {
            int row = m0 + wv * 32 + mt * 16 + quad * 4 + r;
#pragma unroll
            for (int nt = 0; nt < 8; nt++) {
                int col = nt * 16 + lm;
                out[(size_t)row * OUT_F + col] = acc[mt][nt][r] + cb[nt];
            }
        }
}

// ---------------------------------------------------------------------------
extern "C" void kernel_launch(void* const* d_in, const int* in_sizes, int n_in,
                              void* d_out, int out_size, void* d_ws, size_t ws_size,
                              hipStream_t stream) {
    const float* x    = (const float*)d_in[0];
    const int*   ei   = (const int*)d_in[1];
    const float* Wb   = (const float*)d_in[2];
    const float* bb   = (const float*)d_in[3];
    const float* W1   = (const float*)d_in[4];
    const float* b1   = (const float*)d_in[5];
    const float* W2   = (const float*)d_in[6];
    const float* b2   = (const float*)d_in[7];
    const float* bg   = (const float*)d_in[8];
    const float* temp = (const float*)d_in[9];
    const float* Wo   = (const float*)d_in[10];
    const float* bo   = (const float*)d_in[11];
    float* out = (float*)d_out;

    char* w = (char*)d_ws;
    size_t used = 0;
    auto alloc = [&](size_t bytes) {
        char* p = w + used;
        used += (bytes + 255) & ~(size_t)255;
        return p;
    };
    // cursor + cvec contiguous -> single memset zeroes both
    int*    cursor = (int*)alloc(N_NODES * 4);          // final value == deg
    float*  cvec   = (float*)alloc(OUT_F * 4);
    int*    srcs   = (int*)alloc((size_t)N_NODES * STRIDE * 4);
    float*  m2v    = (float*)alloc(N_NODES * 4);
    float*  m3v    = (float*)alloc(N_NODES * 4);
    float*  u      = (float*)alloc(NB * OUT_F * 4);
    ushort* WcT    = (ushort*)alloc((size_t)NB * IN_F * OUT_F * 2);
    ushort* WzT    = (ushort*)alloc((size_t)NB * OUT_F * OUT_F * 2);
    ushort* xb     = (ushort*)alloc((size_t)N_NODES * IN_F * 2);
    ushort* X1b    = (ushort*)alloc((size_t)N_NODES * IN_F * 2);
    ushort* PQ     = (ushort*)alloc((size_t)N_NODES * IN_F * 2);
    ushort* Qp     = (ushort*)alloc((size_t)N_NODES * OUT_F * 2);
    ushort* R      = (ushort*)alloc((size_t)N_NODES * NB * OUT_F * 2);
    if (used > ws_size) return;

    int* deg = cursor;  // alias: cursor holds final degree after fill

    hipMemsetAsync(cursor, 0, N_NODES * 4 + 512, stream);  // cursor + cvec

    fill_all_kernel<<<NE_BLK + CONV_BLK + 104, 256, 0, stream>>>(
        ei, cursor, srcs, x, xb, Wb, W1, W2, Wo, bb, b2, bo, bg, temp, WcT, WzT, u, cvec);

    // X1 = A.x ; m2 = A.(deg>0)
    prop_x_kernel<<<GX_BLK + M_BLK, 256, 0, stream>>>(xb, X1b, deg, m2v, srcs);

    // all 4 branch GEMMs: cols 0,1 of R final; PQ staging for branches 2,3
    {
        dim3 grid(GEMM_BLK, 4);
        gemmP_kernel<<<grid, 256, 0, stream>>>(xb, X1b, WcT, u, b1, deg, R, PQ);
    }

    // A.[P2|Q3]: branch-2 epilogue -> R col2, Q' -> Qp ; m3 = A.m2
    prop_pq_kernel<<<GX_BLK + M_BLK, 256, 0, stream>>>(
        PQ, R, Qp, deg, m2v, m3v, u + 2 * OUT_F, b1 + 2 * OUT_F, srcs);

    // A.Q' with branch-3 epilogue (128-dim gather)
    prop_q_kernel<<<GX_BLK, 256, 0, stream>>>(
        Qp, R, deg, m3v, u + 3 * OUT_F, b1 + 3 * OUT_F, srcs);

    gemm2_mfma_kernel<<<GEMM_BLK, 256, 0, stream>>>(R, WzT, cvec, out);
}